// Round 11
// baseline (85.631 us; speedup 1.0000x reference)
//
#include <hip/hip_runtime.h>

// Chamfer reconstruction loss, B=16, P=Q=4096, 3-D points, via bf16 MFMA.
//
// R20: R18 (verified 81.4us) + atomic-free col-min path ONLY. R19 tried
// this plus a sub-merge that doubled asm-output register pressure to
// ~200 VGPRs and corrupted (like R10: pressure + opaque asm). R20 keeps
// R18's sub loop / single asm block / mn[16] verbatim (+4 regs only).
//
// Col path: per 32-col tile group, fold16 each C tile -> 32-row min per
// col per half, shfl_xor(32) combines halves, then lanes 0-31 write a
// per-wave PRIVATE LDS array (bank==lane, conflict-free): sub 0 plain
// store, sub 1 same-wave load-fmin-store (no race, no atomic). This
// removes R18's 4 ds_atomic_min/iter (2-way same-address RMW, 4 waves
// x 2 subs on one shared array) — the prime suspect for the ~4x gap
// over the ~7us instruction-count floor that survived occupancy (R16),
// AGPR pinning (R17), and addressing (R18) fixes.
// Epilogue fmins the 4 wave arrays into colws (plain float now; the
// int +1.0 ordering trick is gone). combine_kernel decodes floats.

#define NB 16
#define NP 4096
#define NT 2048          // gt cols staged per block (2 slabs)
#define THREADS 256
#define NROWST 65536     // 16 b * 4096 gen rows
#define INV128 0.0078125f   // gt normalize: c/128 - 1
#define FINF __int_as_float(0x7F800000)

typedef __attribute__((ext_vector_type(8)))  short bf16x8;
typedef __attribute__((ext_vector_type(16))) float f32x16;

__device__ __forceinline__ short bf16rne(float f) {
    unsigned u = __float_as_uint(f);
    return (short)((u + 0x7FFFu + ((u >> 16) & 1u)) >> 16);
}
__device__ __forceinline__ float bf2f(short s) {
    return __uint_as_float(((unsigned)(unsigned short)s) << 16);
}
__device__ __forceinline__ float fold16(const f32x16& c) {
    // min3-friendly 16->1 fold (all operands VGPR)
    float a = fminf(fminf(c[0],  c[1]),  c[2]);
    float b = fminf(fminf(c[3],  c[4]),  c[5]);
    float d = fminf(fminf(c[6],  c[7]),  c[8]);
    float e = fminf(fminf(c[9],  c[10]), c[11]);
    float f = fminf(fminf(c[12], c[13]), c[14]);
    float g = fminf(fminf(a, b), c[15]);
    float h = fminf(fminf(d, e), f);
    return fminf(g, h);
}

// grid = 512: b = bid>>5, rs = (bid>>1)&15, cs = bid&1.
// Block: gen rows [rs*256, +256) x gt cols [cs*2048, +2048) of batch b.
__global__ __launch_bounds__(THREADS) void chamfer_kernel(const float* __restrict__ gen,
                                                          const float* __restrict__ label,
                                                          float* __restrict__ rowws,
                                                          float* __restrict__ colws) {
    // 32KB pack + 4 ones-lines + prefetch-overrun pad
    __shared__ short spack[NT * 8 + 1280];
    // per-wave private col-mins (4 x 8KB); sub0 writes every slot -> no init
    __shared__ float colmW[4 * NT];

    const int bid  = blockIdx.x;
    const int b    = bid >> 5;
    const int rs   = (bid >> 1) & 15;
    const int cs   = bid & 1;
    const int tid  = threadIdx.x;
    const int lane = tid & 63;
    const int wave = tid >> 6;            // 0..3
    const int base  = b * NP;
    const int tbase = base + cs * NT;     // first staged gt point

    // FOUR ones-lines at NT*8 + {0,256,512,768} shorts: the high-lane
    // fixed base reads these via the same +256/+512/+768 immediates as
    // the low-lane tile stream. Each line = {1,1,0,0,0,0,0,0} so B
    // k8-15 pairs with A high-lane {q2h,q2l,0,...} to add |q|^2.
    if (tid < 32)
        spack[NT * 8 + (tid >> 3) * 256 + (tid & 7)] =
            ((tid & 7) < 2) ? (short)0x3F80 : (short)0;

    // ---- pack 2048 gt targets: [t_hi xyz, t_lo xyz, t2_hi, t2_lo] ----
    #pragma unroll 4
    for (int k = 0; k < 8; ++k) {
        int j = tid + k * 256;
        const float* row = label + (size_t)(tbase + j) * 5;
        float x = fmaf(row[1], INV128, -1.0f);
        float y = fmaf(row[2], INV128, -1.0f);
        float z = fmaf(row[3], INV128, -1.0f);
        float t2 = fmaf(x, x, fmaf(y, y, z * z));
        short xh = bf16rne(x), yh = bf16rne(y), zh = bf16rne(z);
        short xl = bf16rne(x - bf2f(xh));
        short yl = bf16rne(y - bf2f(yh));
        short zl = bf16rne(z - bf2f(zh));
        short th = bf16rne(t2);
        short tl = bf16rne(t2 - bf2f(th));
        bf16x8 v = {xh, yh, zh, xl, yl, zl, th, tl};
        *(bf16x8*)(spack + j * 8) = v;
    }
    __syncthreads();                      // spack ready

    f32x16 zc = {};                       // persistent all-zero VGPR tuple

    #pragma unroll 1
    for (int sub = 0; sub < 2; ++sub) {
        // ---- per-lane query (gen) fragment: rows = lane&31 ----
        const int qrow = base + rs * 256 + sub * 128 + wave * 32 + (lane & 31);
        const float* g = gen + (size_t)qrow * 3;
        float x = g[0], y = g[1], z = g[2];
        float q2 = fmaf(x, x, fmaf(y, y, z * z));
        bf16x8 afrag;
        if (lane < 32) {                  // k0-7: -2q twice + 1,1 for t2
            short ax = bf16rne(-2.0f * x), ay = bf16rne(-2.0f * y), az = bf16rne(-2.0f * z);
            const short one = 0x3F80;
            bf16x8 a = {ax, ay, az, ax, ay, az, one, one};
            afrag = a;
        } else {                          // k8-15: q2 hi/lo against B ones
            short qh = bf16rne(q2);
            short ql = bf16rne(q2 - bf2f(qh));
            bf16x8 a = {qh, ql, 0, 0, 0, 0, 0, 0};
            afrag = a;
        }

        float mn[16];
        #pragma unroll
        for (int r = 0; r < 16; ++r) mn[r] = FINF;

        // ---- stream 64 col-tiles, 4/iter: ONE 32-bit index, +256/512/768
        // folded into ds_read immediates; register double-buffered ----
        const int obase = (lane < 32) ? ((lane & 31) * 8) : (NT * 8);
        const int step  = (lane < 32) ? 1024 : 0;   // 4 tiles = 128 cols * 8 shorts
        int off = obase;

        bf16x8 b0 = *(const bf16x8*)(spack + off);
        bf16x8 b1 = *(const bf16x8*)(spack + off + 256);
        bf16x8 b2 = *(const bf16x8*)(spack + off + 512);
        bf16x8 b3 = *(const bf16x8*)(spack + off + 768);
        #pragma unroll 2
        for (int it = 0; it < 16; ++it) {
            off += step;
            bf16x8 n0 = *(const bf16x8*)(spack + off);        // last iter: dead
            bf16x8 n1 = *(const bf16x8*)(spack + off + 256);  //   reads into pad
            bf16x8 n2 = *(const bf16x8*)(spack + off + 512);
            bf16x8 n3 = *(const bf16x8*)(spack + off + 768);
            // 4 MFMAs with C/D pinned to arch VGPRs ("v"); earlyclobber
            // keeps outputs disjoint from inputs; s_nops cover the
            // MFMA->VALU-read hazard for the last result.
            f32x16 c0, c1, c2, c3;
            asm("v_mfma_f32_32x32x16_bf16 %0, %4, %5, %9\n\t"
                "v_mfma_f32_32x32x16_bf16 %1, %4, %6, %9\n\t"
                "v_mfma_f32_32x32x16_bf16 %2, %4, %7, %9\n\t"
                "v_mfma_f32_32x32x16_bf16 %3, %4, %8, %9\n\t"
                "s_nop 7\n\t"
                "s_nop 7\n\t"
                "s_nop 3"
                : "=&v"(c0), "=&v"(c1), "=&v"(c2), "=&v"(c3)
                : "v"(afrag), "v"(b0), "v"(b1), "v"(b2), "v"(b3), "v"(zc));
            // row-mins (min over cols, per output row-class) — 2 min3/r
            #pragma unroll
            for (int r = 0; r < 16; ++r) {
                mn[r] = fminf(fminf(c0[r], c1[r]), mn[r]);
                mn[r] = fminf(fminf(c2[r], c3[r]), mn[r]);
            }
            // col-mins without atomics: fold 16 regs -> 1 (min over this
            // half's 16 rows), combine halves via shfl_xor(32) -> 32-row
            // min per col, then write the per-wave PRIVATE region:
            // sub0 plain store, sub1 same-wave load-fmin-store.
            float f0 = fold16(c0), f1 = fold16(c1), f2 = fold16(c2), f3 = fold16(c3);
            f0 = fminf(f0, __shfl_xor(f0, 32, 64));
            f1 = fminf(f1, __shfl_xor(f1, 32, 64));
            f2 = fminf(f2, __shfl_xor(f2, 32, 64));
            f3 = fminf(f3, __shfl_xor(f3, 32, 64));
            if (lane < 32) {
                const int cb = wave * NT + it * 128 + lane;
                if (sub == 0) {
                    colmW[cb]      = f0;
                    colmW[cb + 32] = f1;
                    colmW[cb + 64] = f2;
                    colmW[cb + 96] = f3;
                } else {
                    colmW[cb]      = fminf(colmW[cb],      f0);
                    colmW[cb + 32] = fminf(colmW[cb + 32], f1);
                    colmW[cb + 64] = fminf(colmW[cb + 64], f2);
                    colmW[cb + 96] = fminf(colmW[cb + 96], f3);
                }
            }
            b0 = n0; b1 = n1; b2 = n2; b3 = n3;
        }

        // ---- fold 32 column-classes (butterfly within each 32-lane half) ----
        #pragma unroll
        for (int m = 1; m <= 16; m <<= 1) {
            #pragma unroll
            for (int r = 0; r < 16; ++r)
                mn[r] = fminf(mn[r], __shfl_xor(mn[r], m, 64));
        }

        // ---- write per-row min (mn already includes q2) ----
        // C/D layout: row = (r&3) + 8*(r>>2) + 4*(lane>>5), col = lane&31.
        const int h4 = (lane >> 5) * 4;
        const int c  = lane & 31;
        const int row = (c & 3) + 8 * (c >> 2) + h4;     // valid for c<16
        float v = mn[0];
        #pragma unroll
        for (int r = 1; r < 16; ++r) if (c == r) v = mn[r];  // cndmask chain
        if (c < 16)
            rowws[cs * NROWST + base + rs * 256 + sub * 128 + wave * 32 + row] = v;
    }

    // ---- col epilogue: fmin the 4 private arrays -> colws ----
    __syncthreads();                      // all waves' sub1 writes visible
    const int cwbase = ((b * 2 + cs) * 16 + rs) * NT;
    #pragma unroll
    for (int k = 0; k < 8; ++k) {
        int cc = tid + k * 256;
        float m = fminf(fminf(colmW[cc],          colmW[NT + cc]),
                        fminf(colmW[2 * NT + cc], colmW[3 * NT + cc]));
        colws[cwbase + cc] = m;
    }
}

// grid 512: bid<256 -> row-mins (min over 2 colslabs, already include q2);
//           bid>=256 -> col-mins (min over 16 rowslab partial mins).
__global__ __launch_bounds__(256) void combine_kernel(const float* __restrict__ rowws,
                                                      const float* __restrict__ colws,
                                                      float* __restrict__ partial2) {
    const int tid = threadIdx.x;
    const int bid = blockIdx.x;
    float s;
    if (bid < 256) {
        int row = bid * 256 + tid;        // 0..65535
        s = fminf(rowws[row], rowws[NROWST + row]);
    } else {
        int gidx = (bid - 256) * 256 + tid;   // global gt col 0..65535
        const float* cw = colws + (gidx >> 11) * (16 * NT) + (gidx & (NT - 1));
        float k = cw[0];
        #pragma unroll
        for (int r2 = 1; r2 < 16; ++r2) k = fminf(k, cw[r2 * NT]);
        s = k;
    }
    #pragma unroll
    for (int off = 32; off > 0; off >>= 1) s += __shfl_down(s, off, 64);
    __shared__ float w4[4];
    if ((tid & 63) == 0) w4[tid >> 6] = s;
    __syncthreads();
    if (tid == 0) partial2[bid] = (w4[0] + w4[1]) + (w4[2] + w4[3]);
}

__global__ __launch_bounds__(256) void reduce_kernel(const float* __restrict__ partial,
                                                     float* __restrict__ out) {
    int i = threadIdx.x;
    float s = partial[i] + partial[i + 256];  // 512 partials
    #pragma unroll
    for (int off = 32; off > 0; off >>= 1) s += __shfl_down(s, off, 64);
    __shared__ float ws4[4];
    if ((i & 63) == 0) ws4[i >> 6] = s;
    __syncthreads();
    if (i == 0) out[0] = ((ws4[0] + ws4[1]) + (ws4[2] + ws4[3])) * (1.0f / 65536.0f);
}

extern "C" void kernel_launch(void* const* d_in, const int* in_sizes, int n_in,
                              void* d_out, int out_size, void* d_ws, size_t ws_size,
                              hipStream_t stream) {
    const float* gen   = (const float*)d_in[0];   // [B*P, 3] fp32
    // d_in[1] = batch_gen (int32) — unused: segments are contiguous equal-size
    const float* label = (const float*)d_in[2];   // [B*Q, 5] fp32
    float* rowws    = (float*)d_ws;               // 2*65536 floats  (512 KB)
    float* colws    = (float*)d_ws + 2 * NROWST;  // 16b*2cs*16rs*2048 floats (4 MB)
    float* partial2 = (float*)d_ws + 2 * NROWST + NB * 2 * 16 * NT;  // 512 floats
    float* out = (float*)d_out;

    chamfer_kernel<<<512, THREADS, 0, stream>>>(gen, label, rowws, colws);
    combine_kernel<<<512, 256, 0, stream>>>(rowws, colws, partial2);
    reduce_kernel<<<1, 256, 0, stream>>>(partial2, out);
}

// Round 13
// 84.906 us; speedup vs baseline: 1.0085x; 1.0085x over previous
//
#include <hip/hip_runtime.h>

// Chamfer reconstruction loss, B=16, P=Q=4096, 3-D points, via bf16 MFMA.
//
// R22 == R21 resubmitted verbatim (round-12 bench was an infra failure:
// "MI355X container failed twice" — kernel never compiled or ran).
//
// R21 = R18 (best verified, 81.4us) + reduce_kernel merged into
// combine_kernel via one device atomicAdd per block into out[0] (harness
// memsets out to 0 before launch). R20's atomic-free col path was a
// regression (+4.2us: the 4 extra shfl_xor(32) per iter are serial
// LDS-latency ops) -> ds_atomic_min path restored verbatim.
//
// Ledger of falsified theories for the remaining ~19us chamfer gap over
// the ~8us issue floor: occupancy/TLP (R14,R16 flat), AGPR-read tax
// dominant (R17: ~4us only), flat-load addressing (R18: ~2us), LDS
// atomic serialization (R20: negative). Kernel behaves issue/latency-
// serial; further structural probes need disasm evidence.

#define NB 16
#define NP 4096
#define NT 2048          // gt cols staged per block (2 slabs)
#define THREADS 256
#define NROWST 65536     // 16 b * 4096 gen rows
#define INV128 0.0078125f   // gt normalize: c/128 - 1
#define FINF __int_as_float(0x7F800000)

typedef __attribute__((ext_vector_type(8)))  short bf16x8;
typedef __attribute__((ext_vector_type(16))) float f32x16;

__device__ __forceinline__ short bf16rne(float f) {
    unsigned u = __float_as_uint(f);
    return (short)((u + 0x7FFFu + ((u >> 16) & 1u)) >> 16);
}
__device__ __forceinline__ float bf2f(short s) {
    return __uint_as_float(((unsigned)(unsigned short)s) << 16);
}
__device__ __forceinline__ float fold16(const f32x16& c) {
    // min3-friendly 16->1 fold (all operands VGPR)
    float a = fminf(fminf(c[0],  c[1]),  c[2]);
    float b = fminf(fminf(c[3],  c[4]),  c[5]);
    float d = fminf(fminf(c[6],  c[7]),  c[8]);
    float e = fminf(fminf(c[9],  c[10]), c[11]);
    float f = fminf(fminf(c[12], c[13]), c[14]);
    float g = fminf(fminf(a, b), c[15]);
    float h = fminf(fminf(d, e), f);
    return fminf(g, h);
}

// grid = 512: b = bid>>5, rs = (bid>>1)&15, cs = bid&1.
// Block: gen rows [rs*256, +256) x gt cols [cs*2048, +2048) of batch b.
__global__ __launch_bounds__(THREADS) void chamfer_kernel(const float* __restrict__ gen,
                                                          const float* __restrict__ label,
                                                          float* __restrict__ rowws,
                                                          int* __restrict__ colws) {
    // 32KB pack + 4 ones-lines + prefetch-overrun pad + 8KB col-min keys
    __shared__ short spack[NT * 8 + 1280];
    __shared__ int colmin[NT];

    const int bid  = blockIdx.x;
    const int b    = bid >> 5;
    const int rs   = (bid >> 1) & 15;
    const int cs   = bid & 1;
    const int tid  = threadIdx.x;
    const int lane = tid & 63;
    const int wave = tid >> 6;            // 0..3
    const int base  = b * NP;
    const int tbase = base + cs * NT;     // first staged gt point

    // FOUR ones-lines at NT*8 + {0,256,512,768} shorts: the high-lane
    // fixed base reads these via the same +256/+512/+768 immediates as
    // the low-lane tile stream. Each line = {1,1,0,0,0,0,0,0} so B
    // k8-15 pairs with A high-lane {q2h,q2l,0,...} to add |q|^2.
    if (tid < 32)
        spack[NT * 8 + (tid >> 3) * 256 + (tid & 7)] =
            ((tid & 7) < 2) ? (short)0x3F80 : (short)0;

    #pragma unroll
    for (int k = 0; k < 8; ++k) colmin[tid + k * 256] = 0x7F800000;  // +inf key

    // ---- pack 2048 gt targets: [t_hi xyz, t_lo xyz, t2_hi, t2_lo] ----
    #pragma unroll 4
    for (int k = 0; k < 8; ++k) {
        int j = tid + k * 256;
        const float* row = label + (size_t)(tbase + j) * 5;
        float x = fmaf(row[1], INV128, -1.0f);
        float y = fmaf(row[2], INV128, -1.0f);
        float z = fmaf(row[3], INV128, -1.0f);
        float t2 = fmaf(x, x, fmaf(y, y, z * z));
        short xh = bf16rne(x), yh = bf16rne(y), zh = bf16rne(z);
        short xl = bf16rne(x - bf2f(xh));
        short yl = bf16rne(y - bf2f(yh));
        short zl = bf16rne(z - bf2f(zh));
        short th = bf16rne(t2);
        short tl = bf16rne(t2 - bf2f(th));
        bf16x8 v = {xh, yh, zh, xl, yl, zl, th, tl};
        *(bf16x8*)(spack + j * 8) = v;
    }
    __syncthreads();                      // spack + colmin ready

    f32x16 zc = {};                       // persistent all-zero VGPR tuple

    #pragma unroll 1
    for (int sub = 0; sub < 2; ++sub) {
        // ---- per-lane query (gen) fragment: rows = lane&31 ----
        const int qrow = base + rs * 256 + sub * 128 + wave * 32 + (lane & 31);
        const float* g = gen + (size_t)qrow * 3;
        float x = g[0], y = g[1], z = g[2];
        float q2 = fmaf(x, x, fmaf(y, y, z * z));
        bf16x8 afrag;
        if (lane < 32) {                  // k0-7: -2q twice + 1,1 for t2
            short ax = bf16rne(-2.0f * x), ay = bf16rne(-2.0f * y), az = bf16rne(-2.0f * z);
            const short one = 0x3F80;
            bf16x8 a = {ax, ay, az, ax, ay, az, one, one};
            afrag = a;
        } else {                          // k8-15: q2 hi/lo against B ones
            short qh = bf16rne(q2);
            short ql = bf16rne(q2 - bf2f(qh));
            bf16x8 a = {qh, ql, 0, 0, 0, 0, 0, 0};
            afrag = a;
        }

        float mn[16];
        #pragma unroll
        for (int r = 0; r < 16; ++r) mn[r] = FINF;

        // ---- stream 64 col-tiles, 4/iter: ONE 32-bit index, +256/512/768
        // folded into ds_read immediates; register double-buffered ----
        const int obase = (lane < 32) ? ((lane & 31) * 8) : (NT * 8);
        const int step  = (lane < 32) ? 1024 : 0;   // 4 tiles = 128 cols * 8 shorts
        int off = obase;

        bf16x8 b0 = *(const bf16x8*)(spack + off);
        bf16x8 b1 = *(const bf16x8*)(spack + off + 256);
        bf16x8 b2 = *(const bf16x8*)(spack + off + 512);
        bf16x8 b3 = *(const bf16x8*)(spack + off + 768);
        #pragma unroll 2
        for (int it = 0; it < 16; ++it) {
            off += step;
            bf16x8 n0 = *(const bf16x8*)(spack + off);        // last iter: dead
            bf16x8 n1 = *(const bf16x8*)(spack + off + 256);  //   reads into pad
            bf16x8 n2 = *(const bf16x8*)(spack + off + 512);
            bf16x8 n3 = *(const bf16x8*)(spack + off + 768);
            // 4 MFMAs with C/D pinned to arch VGPRs ("v"); earlyclobber
            // keeps outputs disjoint from inputs; s_nops cover the
            // MFMA->VALU-read hazard for the last result.
            f32x16 c0, c1, c2, c3;
            asm("v_mfma_f32_32x32x16_bf16 %0, %4, %5, %9\n\t"
                "v_mfma_f32_32x32x16_bf16 %1, %4, %6, %9\n\t"
                "v_mfma_f32_32x32x16_bf16 %2, %4, %7, %9\n\t"
                "v_mfma_f32_32x32x16_bf16 %3, %4, %8, %9\n\t"
                "s_nop 7\n\t"
                "s_nop 7\n\t"
                "s_nop 3"
                : "=&v"(c0), "=&v"(c1), "=&v"(c2), "=&v"(c3)
                : "v"(afrag), "v"(b0), "v"(b1), "v"(b2), "v"(b3), "v"(zc));
            // row-mins (min over cols, per output row-class) — 2 min3/r
            #pragma unroll
            for (int r = 0; r < 16; ++r) {
                mn[r] = fminf(fminf(c0[r], c1[r]), mn[r]);
                mn[r] = fminf(fminf(c2[r], c3[r]), mn[r]);
            }
            // col-mins (min over this wave's 32 rows, per col): fold 16
            // regs -> 1, then LDS atomicMin of float_as_int(d+1) — both
            // lane halves hit the same col (2-way, HW-serialized).
            const int cb = it * 128 + (lane & 31);
            atomicMin(&colmin[cb],       __float_as_int(fold16(c0) + 1.0f));
            atomicMin(&colmin[cb + 32],  __float_as_int(fold16(c1) + 1.0f));
            atomicMin(&colmin[cb + 64],  __float_as_int(fold16(c2) + 1.0f));
            atomicMin(&colmin[cb + 96],  __float_as_int(fold16(c3) + 1.0f));
            b0 = n0; b1 = n1; b2 = n2; b3 = n3;
        }

        // ---- fold 32 column-classes (butterfly within each 32-lane half) ----
        #pragma unroll
        for (int m = 1; m <= 16; m <<= 1) {
            #pragma unroll
            for (int r = 0; r < 16; ++r)
                mn[r] = fminf(mn[r], __shfl_xor(mn[r], m, 64));
        }

        // ---- write per-row min (mn already includes q2) ----
        // C/D layout: row = (r&3) + 8*(r>>2) + 4*(lane>>5), col = lane&31.
        const int h4 = (lane >> 5) * 4;
        const int c  = lane & 31;
        const int row = (c & 3) + 8 * (c >> 2) + h4;     // valid for c<16
        float v = mn[0];
        #pragma unroll
        for (int r = 1; r < 16; ++r) if (c == r) v = mn[r];  // cndmask chain
        if (c < 16)
            rowws[cs * NROWST + base + rs * 256 + sub * 128 + wave * 32 + row] = v;
    }

    __syncthreads();                      // all col atomics done
    const int cwbase = ((b * 2 + cs) * 16 + rs) * NT;
    #pragma unroll
    for (int k = 0; k < 8; ++k)
        colws[cwbase + tid + k * 256] = colmin[tid + k * 256];
}

// grid 512: bid<256 -> row-mins (min over 2 colslabs, already include q2);
//           bid>=256 -> col-mins (min over 16 rowslab int keys, decode).
// Each block atomically adds its scaled partial into out[0] (harness
// memsets out to 0 before launch) — reduce_kernel eliminated.
__global__ __launch_bounds__(256) void combine_kernel(const float* __restrict__ rowws,
                                                      const int* __restrict__ colws,
                                                      float* __restrict__ out) {
    const int tid = threadIdx.x;
    const int bid = blockIdx.x;
    float s;
    if (bid < 256) {
        int row = bid * 256 + tid;        // 0..65535
        s = fminf(rowws[row], rowws[NROWST + row]);
    } else {
        int gidx = (bid - 256) * 256 + tid;   // global gt col 0..65535
        const int* cw = colws + (gidx >> 11) * (16 * NT) + (gidx & (NT - 1));
        int k = cw[0];
        #pragma unroll
        for (int r2 = 1; r2 < 16; ++r2) k = min(k, cw[r2 * NT]);
        s = __int_as_float(k) - 1.0f;     // undo the +1 positivity shift
    }
    #pragma unroll
    for (int off = 32; off > 0; off >>= 1) s += __shfl_down(s, off, 64);
    __shared__ float w4[4];
    if ((tid & 63) == 0) w4[tid >> 6] = s;
    __syncthreads();
    if (tid == 0)
        atomicAdd(out, ((w4[0] + w4[1]) + (w4[2] + w4[3])) * (1.0f / 65536.0f));
}

extern "C" void kernel_launch(void* const* d_in, const int* in_sizes, int n_in,
                              void* d_out, int out_size, void* d_ws, size_t ws_size,
                              hipStream_t stream) {
    const float* gen   = (const float*)d_in[0];   // [B*P, 3] fp32
    // d_in[1] = batch_gen (int32) — unused: segments are contiguous equal-size
    const float* label = (const float*)d_in[2];   // [B*Q, 5] fp32
    float* rowws = (float*)d_ws;                  // 2*65536 floats  (512 KB)
    int*   colws = (int*)d_ws + 2 * NROWST;       // 16b*2cs*16rs*2048 ints (4 MB)
    float* out = (float*)d_out;

    chamfer_kernel<<<512, THREADS, 0, stream>>>(gen, label, rowws, colws);
    combine_kernel<<<512, 256, 0, stream>>>(rowws, colws, out);
}

// Round 14
// 81.336 us; speedup vs baseline: 1.0528x; 1.0439x over previous
//
#include <hip/hip_runtime.h>

// Chamfer reconstruction loss, B=16, P=Q=4096, 3-D points, via bf16 MFMA.
//
// R23 == R18 verbatim (best verified config, 81.4us). R22's reduce-merge
// via 512 device-scope atomicAdds to out[0] measured 84.9 (predicted
// ~78): single-address cross-XCD atomic burst or noise — reverted.
//
// R18: R15's one-matrix/two-reductions structure (row-mins + col-mins of
// one D[gen x gt] per batch; |q|^2 in-matrix via k8-15 + ones-line B),
// asm-MFMA with C/D pinned in arch VGPRs (R17), LDS stream via ONE
// 32-bit index with +256/512/768 ds_read immediates (R18).
//
// Ledger of falsified theories for the remaining ~19us chamfer gap over
// the ~8us issue floor: occupancy/TLP (R14,R16 flat), AGPR-read tax
// dominant (R17: ~4us only), flat-load addressing (R18: ~2us), LDS
// atomic serialization (R20: negative), reduce-merge (R22: negative).
// ~41us of total is harness ws re-poison at 83% HBM peak (untouchable).

#define NB 16
#define NP 4096
#define NT 2048          // gt cols staged per block (2 slabs)
#define THREADS 256
#define NROWST 65536     // 16 b * 4096 gen rows
#define INV128 0.0078125f   // gt normalize: c/128 - 1
#define FINF __int_as_float(0x7F800000)

typedef __attribute__((ext_vector_type(8)))  short bf16x8;
typedef __attribute__((ext_vector_type(16))) float f32x16;

__device__ __forceinline__ short bf16rne(float f) {
    unsigned u = __float_as_uint(f);
    return (short)((u + 0x7FFFu + ((u >> 16) & 1u)) >> 16);
}
__device__ __forceinline__ float bf2f(short s) {
    return __uint_as_float(((unsigned)(unsigned short)s) << 16);
}
__device__ __forceinline__ float fold16(const f32x16& c) {
    // min3-friendly 16->1 fold (all operands VGPR)
    float a = fminf(fminf(c[0],  c[1]),  c[2]);
    float b = fminf(fminf(c[3],  c[4]),  c[5]);
    float d = fminf(fminf(c[6],  c[7]),  c[8]);
    float e = fminf(fminf(c[9],  c[10]), c[11]);
    float f = fminf(fminf(c[12], c[13]), c[14]);
    float g = fminf(fminf(a, b), c[15]);
    float h = fminf(fminf(d, e), f);
    return fminf(g, h);
}

// grid = 512: b = bid>>5, rs = (bid>>1)&15, cs = bid&1.
// Block: gen rows [rs*256, +256) x gt cols [cs*2048, +2048) of batch b.
__global__ __launch_bounds__(THREADS) void chamfer_kernel(const float* __restrict__ gen,
                                                          const float* __restrict__ label,
                                                          float* __restrict__ rowws,
                                                          int* __restrict__ colws) {
    // 32KB pack + 4 ones-lines + prefetch-overrun pad + 8KB col-min keys
    __shared__ short spack[NT * 8 + 1280];
    __shared__ int colmin[NT];

    const int bid  = blockIdx.x;
    const int b    = bid >> 5;
    const int rs   = (bid >> 1) & 15;
    const int cs   = bid & 1;
    const int tid  = threadIdx.x;
    const int lane = tid & 63;
    const int wave = tid >> 6;            // 0..3
    const int base  = b * NP;
    const int tbase = base + cs * NT;     // first staged gt point

    // FOUR ones-lines at NT*8 + {0,256,512,768} shorts: the high-lane
    // fixed base reads these via the same +256/+512/+768 immediates as
    // the low-lane tile stream. Each line = {1,1,0,0,0,0,0,0} so B
    // k8-15 pairs with A high-lane {q2h,q2l,0,...} to add |q|^2.
    if (tid < 32)
        spack[NT * 8 + (tid >> 3) * 256 + (tid & 7)] =
            ((tid & 7) < 2) ? (short)0x3F80 : (short)0;

    #pragma unroll
    for (int k = 0; k < 8; ++k) colmin[tid + k * 256] = 0x7F800000;  // +inf key

    // ---- pack 2048 gt targets: [t_hi xyz, t_lo xyz, t2_hi, t2_lo] ----
    #pragma unroll 4
    for (int k = 0; k < 8; ++k) {
        int j = tid + k * 256;
        const float* row = label + (size_t)(tbase + j) * 5;
        float x = fmaf(row[1], INV128, -1.0f);
        float y = fmaf(row[2], INV128, -1.0f);
        float z = fmaf(row[3], INV128, -1.0f);
        float t2 = fmaf(x, x, fmaf(y, y, z * z));
        short xh = bf16rne(x), yh = bf16rne(y), zh = bf16rne(z);
        short xl = bf16rne(x - bf2f(xh));
        short yl = bf16rne(y - bf2f(yh));
        short zl = bf16rne(z - bf2f(zh));
        short th = bf16rne(t2);
        short tl = bf16rne(t2 - bf2f(th));
        bf16x8 v = {xh, yh, zh, xl, yl, zl, th, tl};
        *(bf16x8*)(spack + j * 8) = v;
    }
    __syncthreads();                      // spack + colmin ready

    f32x16 zc = {};                       // persistent all-zero VGPR tuple

    #pragma unroll 1
    for (int sub = 0; sub < 2; ++sub) {
        // ---- per-lane query (gen) fragment: rows = lane&31 ----
        const int qrow = base + rs * 256 + sub * 128 + wave * 32 + (lane & 31);
        const float* g = gen + (size_t)qrow * 3;
        float x = g[0], y = g[1], z = g[2];
        float q2 = fmaf(x, x, fmaf(y, y, z * z));
        bf16x8 afrag;
        if (lane < 32) {                  // k0-7: -2q twice + 1,1 for t2
            short ax = bf16rne(-2.0f * x), ay = bf16rne(-2.0f * y), az = bf16rne(-2.0f * z);
            const short one = 0x3F80;
            bf16x8 a = {ax, ay, az, ax, ay, az, one, one};
            afrag = a;
        } else {                          // k8-15: q2 hi/lo against B ones
            short qh = bf16rne(q2);
            short ql = bf16rne(q2 - bf2f(qh));
            bf16x8 a = {qh, ql, 0, 0, 0, 0, 0, 0};
            afrag = a;
        }

        float mn[16];
        #pragma unroll
        for (int r = 0; r < 16; ++r) mn[r] = FINF;

        // ---- stream 64 col-tiles, 4/iter: ONE 32-bit index, +256/512/768
        // folded into ds_read immediates; register double-buffered ----
        const int obase = (lane < 32) ? ((lane & 31) * 8) : (NT * 8);
        const int step  = (lane < 32) ? 1024 : 0;   // 4 tiles = 128 cols * 8 shorts
        int off = obase;

        bf16x8 b0 = *(const bf16x8*)(spack + off);
        bf16x8 b1 = *(const bf16x8*)(spack + off + 256);
        bf16x8 b2 = *(const bf16x8*)(spack + off + 512);
        bf16x8 b3 = *(const bf16x8*)(spack + off + 768);
        #pragma unroll 2
        for (int it = 0; it < 16; ++it) {
            off += step;
            bf16x8 n0 = *(const bf16x8*)(spack + off);        // last iter: dead
            bf16x8 n1 = *(const bf16x8*)(spack + off + 256);  //   reads into pad
            bf16x8 n2 = *(const bf16x8*)(spack + off + 512);
            bf16x8 n3 = *(const bf16x8*)(spack + off + 768);
            // 4 MFMAs with C/D pinned to arch VGPRs ("v"); earlyclobber
            // keeps outputs disjoint from inputs; s_nops cover the
            // MFMA->VALU-read hazard for the last result.
            f32x16 c0, c1, c2, c3;
            asm("v_mfma_f32_32x32x16_bf16 %0, %4, %5, %9\n\t"
                "v_mfma_f32_32x32x16_bf16 %1, %4, %6, %9\n\t"
                "v_mfma_f32_32x32x16_bf16 %2, %4, %7, %9\n\t"
                "v_mfma_f32_32x32x16_bf16 %3, %4, %8, %9\n\t"
                "s_nop 7\n\t"
                "s_nop 7\n\t"
                "s_nop 3"
                : "=&v"(c0), "=&v"(c1), "=&v"(c2), "=&v"(c3)
                : "v"(afrag), "v"(b0), "v"(b1), "v"(b2), "v"(b3), "v"(zc));
            // row-mins (min over cols, per output row-class) — 2 min3/r
            #pragma unroll
            for (int r = 0; r < 16; ++r) {
                mn[r] = fminf(fminf(c0[r], c1[r]), mn[r]);
                mn[r] = fminf(fminf(c2[r], c3[r]), mn[r]);
            }
            // col-mins (min over this wave's 32 rows, per col): fold 16
            // regs -> 1, then LDS atomicMin of float_as_int(d+1) — both
            // lane halves hit the same col (2-way, HW-serialized).
            const int cb = it * 128 + (lane & 31);
            atomicMin(&colmin[cb],       __float_as_int(fold16(c0) + 1.0f));
            atomicMin(&colmin[cb + 32],  __float_as_int(fold16(c1) + 1.0f));
            atomicMin(&colmin[cb + 64],  __float_as_int(fold16(c2) + 1.0f));
            atomicMin(&colmin[cb + 96],  __float_as_int(fold16(c3) + 1.0f));
            b0 = n0; b1 = n1; b2 = n2; b3 = n3;
        }

        // ---- fold 32 column-classes (butterfly within each 32-lane half) ----
        #pragma unroll
        for (int m = 1; m <= 16; m <<= 1) {
            #pragma unroll
            for (int r = 0; r < 16; ++r)
                mn[r] = fminf(mn[r], __shfl_xor(mn[r], m, 64));
        }

        // ---- write per-row min (mn already includes q2) ----
        // C/D layout: row = (r&3) + 8*(r>>2) + 4*(lane>>5), col = lane&31.
        const int h4 = (lane >> 5) * 4;
        const int c  = lane & 31;
        const int row = (c & 3) + 8 * (c >> 2) + h4;     // valid for c<16
        float v = mn[0];
        #pragma unroll
        for (int r = 1; r < 16; ++r) if (c == r) v = mn[r];  // cndmask chain
        if (c < 16)
            rowws[cs * NROWST + base + rs * 256 + sub * 128 + wave * 32 + row] = v;
    }

    __syncthreads();                      // all col atomics done
    const int cwbase = ((b * 2 + cs) * 16 + rs) * NT;
    #pragma unroll
    for (int k = 0; k < 8; ++k)
        colws[cwbase + tid + k * 256] = colmin[tid + k * 256];
}

// grid 512: bid<256 -> row-mins (min over 2 colslabs, already include q2);
//           bid>=256 -> col-mins (min over 16 rowslab int keys, decode).
__global__ __launch_bounds__(256) void combine_kernel(const float* __restrict__ rowws,
                                                      const int* __restrict__ colws,
                                                      float* __restrict__ partial2) {
    const int tid = threadIdx.x;
    const int bid = blockIdx.x;
    float s;
    if (bid < 256) {
        int row = bid * 256 + tid;        // 0..65535
        s = fminf(rowws[row], rowws[NROWST + row]);
    } else {
        int gidx = (bid - 256) * 256 + tid;   // global gt col 0..65535
        const int* cw = colws + (gidx >> 11) * (16 * NT) + (gidx & (NT - 1));
        int k = cw[0];
        #pragma unroll
        for (int r2 = 1; r2 < 16; ++r2) k = min(k, cw[r2 * NT]);
        s = __int_as_float(k) - 1.0f;     // undo the +1 positivity shift
    }
    #pragma unroll
    for (int off = 32; off > 0; off >>= 1) s += __shfl_down(s, off, 64);
    __shared__ float w4[4];
    if ((tid & 63) == 0) w4[tid >> 6] = s;
    __syncthreads();
    if (tid == 0) partial2[bid] = (w4[0] + w4[1]) + (w4[2] + w4[3]);
}

__global__ __launch_bounds__(256) void reduce_kernel(const float* __restrict__ partial,
                                                     float* __restrict__ out) {
    int i = threadIdx.x;
    float s = partial[i] + partial[i + 256];  // 512 partials
    #pragma unroll
    for (int off = 32; off > 0; off >>= 1) s += __shfl_down(s, off, 64);
    __shared__ float ws4[4];
    if ((i & 63) == 0) ws4[i >> 6] = s;
    __syncthreads();
    if (i == 0) out[0] = ((ws4[0] + ws4[1]) + (ws4[2] + ws4[3])) * (1.0f / 65536.0f);
}

extern "C" void kernel_launch(void* const* d_in, const int* in_sizes, int n_in,
                              void* d_out, int out_size, void* d_ws, size_t ws_size,
                              hipStream_t stream) {
    const float* gen   = (const float*)d_in[0];   // [B*P, 3] fp32
    // d_in[1] = batch_gen (int32) — unused: segments are contiguous equal-size
    const float* label = (const float*)d_in[2];   // [B*Q, 5] fp32
    float* rowws    = (float*)d_ws;               // 2*65536 floats  (512 KB)
    int*   colws    = (int*)d_ws + 2 * NROWST;    // 16b*2cs*16rs*2048 ints (4 MB)
    float* partial2 = (float*)d_ws + 2 * NROWST + NB * 2 * 16 * NT;  // 512 floats
    float* out = (float*)d_out;

    chamfer_kernel<<<512, THREADS, 0, stream>>>(gen, label, rowws, colws);
    combine_kernel<<<512, 256, 0, stream>>>(rowws, colws, partial2);
    reduce_kernel<<<1, 256, 0, stream>>>(partial2, out);
}